// Round 1
// baseline (669.858 us; speedup 1.0000x reference)
//
#include <hip/hip_runtime.h>

// Problem constants (fixed by reference)
constexpr int B_ROWS = 65536;
constexpr int IN_F   = 1024;
constexpr int OUT_F  = 1024;

constexpr int BDIM = 256;          // 4 waves
constexpr int BM = 128, BN = 128, BK = 32;
constexpr int LDK = 40;            // padded LDS k-stride (80 B: 16B-aligned, 20 banks -> 2-way only)

typedef __bf16 bf16x8 __attribute__((ext_vector_type(8)));
typedef float  f32x4  __attribute__((ext_vector_type(4)));

__device__ __forceinline__ bf16x8 cvt8(f32x4 u0, f32x4 u1) {
    bf16x8 v;
    v[0] = (__bf16)u0[0]; v[1] = (__bf16)u0[1]; v[2] = (__bf16)u0[2]; v[3] = (__bf16)u0[3];
    v[4] = (__bf16)u1[0]; v[5] = (__bf16)u1[1]; v[6] = (__bf16)u1[2]; v[7] = (__bf16)u1[3];
    return v;
}

__global__ __launch_bounds__(BDIM, 2)
void fused_linear_act(const float* __restrict__ X,    // [B_ROWS][IN_F]
                      const float* __restrict__ W,    // [OUT_F][IN_F]  (oi layout = B^T)
                      const float* __restrict__ bias, // [OUT_F]
                      float* __restrict__ O)          // [B_ROWS][OUT_F]
{
    __shared__ __attribute__((aligned(16))) __bf16 As[BM * LDK];
    __shared__ __attribute__((aligned(16))) __bf16 Bs[BN * LDK];

    const int bx = blockIdx.x;
    const int nt = bx & 7;     // 8 N tiles; consecutive blocks share the A panel (LLC locality)
    const int mt = bx >> 3;    // 512 M tiles
    const int m0 = mt * BM;
    const int n0 = nt * BN;

    const int tid  = threadIdx.x;
    const int lane = tid & 63;
    const int wave = tid >> 6;        // 0..3
    const int wm = (wave >> 1) * 64;  // wave row offset in tile
    const int wn = (wave & 1) * 64;   // wave col offset in tile
    const int lrow = lane & 15;       // A: m, B: n within 16-tile
    const int quad = lane >> 4;       // k-group / row-group for C

    // staging: thread -> (row, 8-float k-segment); 2 passes cover 128 rows
    const int srow = tid >> 2;        // 0..63
    const int sseg = tid & 3;         // k offset = sseg*8 floats

    f32x4 acc[4][4];
    #pragma unroll
    for (int i = 0; i < 4; ++i)
        #pragma unroll
        for (int j = 0; j < 4; ++j)
            acc[i][j] = (f32x4){0.f, 0.f, 0.f, 0.f};

    const float* xa = X + (size_t)(m0 + srow)      * IN_F + sseg * 8;
    const float* xb = X + (size_t)(m0 + srow + 64) * IN_F + sseg * 8;
    const float* wa = W + (size_t)(n0 + srow)      * IN_F + sseg * 8;
    const float* wb = W + (size_t)(n0 + srow + 64) * IN_F + sseg * 8;

    __bf16* as0 = &As[(srow)      * LDK + sseg * 8];
    __bf16* as1 = &As[(srow + 64) * LDK + sseg * 8];
    __bf16* bs0 = &Bs[(srow)      * LDK + sseg * 8];
    __bf16* bs1 = &Bs[(srow + 64) * LDK + sseg * 8];

    const __bf16* aBase = &As[(wm + lrow) * LDK + quad * 8];
    const __bf16* bBase = &Bs[(wn + lrow) * LDK + quad * 8];

    for (int k0 = 0; k0 < IN_F; k0 += BK) {
        // global fp32 loads for next tile (issued before barrier for latency overlap)
        f32x4 a00 = *(const f32x4*)(xa);     f32x4 a01 = *(const f32x4*)(xa + 4);
        f32x4 a10 = *(const f32x4*)(xb);     f32x4 a11 = *(const f32x4*)(xb + 4);
        f32x4 b00 = *(const f32x4*)(wa);     f32x4 b01 = *(const f32x4*)(wa + 4);
        f32x4 b10 = *(const f32x4*)(wb);     f32x4 b11 = *(const f32x4*)(wb + 4);
        xa += BK; xb += BK; wa += BK; wb += BK;

        __syncthreads();   // previous iteration's ds_reads done before overwrite

        *(bf16x8*)as0 = cvt8(a00, a01);
        *(bf16x8*)as1 = cvt8(a10, a11);
        *(bf16x8*)bs0 = cvt8(b00, b01);
        *(bf16x8*)bs1 = cvt8(b10, b11);

        __syncthreads();

        bf16x8 af[4], bf[4];
        #pragma unroll
        for (int t = 0; t < 4; ++t) af[t] = *(const bf16x8*)(aBase + t * 16 * LDK);
        #pragma unroll
        for (int t = 0; t < 4; ++t) bf[t] = *(const bf16x8*)(bBase + t * 16 * LDK);

        #pragma unroll
        for (int i = 0; i < 4; ++i)
            #pragma unroll
            for (int j = 0; j < 4; ++j)
                acc[i][j] = __builtin_amdgcn_mfma_f32_16x16x32_bf16(af[i], bf[j], acc[i][j], 0, 0, 0);
    }

    // Epilogue: bias + cyclic activation. Selector = col%4 = lane&3 (uniform per lane).
    // tanh(y) = 2/(1+e^{-2y})-1 ; sigmoid(y) = 1/(1+e^{-y}) -> common form a*rcp(1+e^{k*y})+c
    const int s = lane & 3;
    const float kmul = (s == 0) ? -2.f : -1.f;
    const float aa   = (s == 0) ?  2.f :  1.f;
    const float cc   = (s == 0) ? -1.f :  0.f;
    const bool  is_sin  = (s == 1);
    const bool  is_relu = (s == 2);

    #pragma unroll
    for (int j = 0; j < 4; ++j) {
        const int gc = n0 + wn + j * 16 + lrow;
        const float bv = bias[gc];
        #pragma unroll
        for (int i = 0; i < 4; ++i) {
            const int gr0 = m0 + wm + i * 16 + quad * 4;
            float* op = O + (size_t)gr0 * OUT_F + gc;
            #pragma unroll
            for (int r = 0; r < 4; ++r) {
                const float y = acc[i][j][r] + bv;
                const float e = __expf(kmul * y);
                const float g = fmaf(aa, __builtin_amdgcn_rcpf(1.f + e), cc);
                const float sv = __sinf(y);
                const float rv = fmaxf(y, 0.f);
                const float res = is_sin ? sv : (is_relu ? rv : g);
                op[(size_t)r * OUT_F] = res;
            }
        }
    }
}

extern "C" void kernel_launch(void* const* d_in, const int* in_sizes, int n_in,
                              void* d_out, int out_size, void* d_ws, size_t ws_size,
                              hipStream_t stream) {
    const float* X = (const float*)d_in[0];
    const float* W = (const float*)d_in[1];
    const float* b = (const float*)d_in[2];
    float* O = (float*)d_out;

    const int grid = (B_ROWS / BM) * (OUT_F / BN);  // 512 * 8 = 4096 blocks
    fused_linear_act<<<grid, BDIM, 0, stream>>>(X, W, b, O);
}

// Round 2
// 638.623 us; speedup vs baseline: 1.0489x; 1.0489x over previous
//
#include <hip/hip_runtime.h>

// Problem constants (fixed by reference)
constexpr int B_ROWS = 65536;
constexpr int IN_F   = 1024;
constexpr int OUT_F  = 1024;

constexpr int BDIM = 256;          // 4 waves
constexpr int BM = 128, BN = 128, BK = 32;

typedef __bf16 bf16x8 __attribute__((ext_vector_type(8)));
typedef float  f32x4  __attribute__((ext_vector_type(4)));

__device__ __forceinline__ bf16x8 cvt8(f32x4 u0, f32x4 u1) {
    bf16x8 v;
    v[0] = (__bf16)u0[0]; v[1] = (__bf16)u0[1]; v[2] = (__bf16)u0[2]; v[3] = (__bf16)u0[3];
    v[4] = (__bf16)u1[0]; v[5] = (__bf16)u1[1]; v[6] = (__bf16)u1[2]; v[7] = (__bf16)u1[3];
    return v;
}

// lgkm-only barrier: LDS writes visible, but prefetch global loads stay in
// flight across it (avoids __syncthreads' vmcnt(0) drain).
#define LDS_SYNC() asm volatile("s_waitcnt lgkmcnt(0)\n\ts_barrier" ::: "memory")

__global__ __launch_bounds__(BDIM, 2)
void fused_linear_act(const float* __restrict__ X,    // [B_ROWS][IN_F]
                      const float* __restrict__ W,    // [OUT_F][IN_F]  (oi = B^T)
                      const float* __restrict__ bias, // [OUT_F]
                      float* __restrict__ O)          // [B_ROWS][OUT_F]
{
    // LDS: 2 buffers x (A 8KB | B 8KB), "MFMA-order" permuted layout:
    // 16B unit(row,kq) = (row>>4)*64 + kq*16 + (row&15). Every wave-level
    // ds_read_b128/ds_write_b128 is a permuted contiguous 1KB block -> 0 conflicts.
    __shared__ __attribute__((aligned(16))) unsigned char lds[2 * 16384];

    const int bx  = blockIdx.x;
    // XCD-aware: round-robin bx%8 -> XCD. Per XCD, 8 consecutive blocks share
    // one A panel (L2 reuse); mt strides by 8 so X rows partition across XCDs.
    const int xcd = bx & 7;
    const int idx = bx >> 3;
    const int nt  = idx & 7;
    const int mt  = xcd + 8 * (idx >> 3);
    const int m0 = mt * BM;
    const int n0 = nt * BN;

    const int tid  = threadIdx.x;
    const int lane = tid & 63;
    const int wave = tid >> 6;
    const int wm = (wave >> 1) * 64;
    const int wn = (wave & 1) * 64;
    const int lrow = lane & 15;
    const int quad = lane >> 4;

    // staging: thread -> (row srow, 8-float k-segment sseg)
    const int srow = tid >> 2;        // 0..63 (+64 for second half)
    const int sseg = tid & 3;

    f32x4 acc[4][4];
    #pragma unroll
    for (int i = 0; i < 4; ++i)
        #pragma unroll
        for (int j = 0; j < 4; ++j)
            acc[i][j] = (f32x4){0.f, 0.f, 0.f, 0.f};

    const float* xa = X + (size_t)(m0 + srow) * IN_F + sseg * 8;
    const float* xb = xa + (size_t)64 * IN_F;
    const float* wa = W + (size_t)(n0 + srow) * IN_F + sseg * 8;
    const float* wb = wa + (size_t)64 * IN_F;

    // one write-address register; all destinations are immediate offsets
    unsigned char* wr = &lds[((srow >> 4) * 64 + sseg * 16 + (srow & 15)) * 16];
    // one read-address register per matrix; frag t at +t*1024
    const unsigned char* rdA = &lds[(wm >> 4) * 1024 + lane * 16];
    const unsigned char* rdB = &lds[8192 + (wn >> 4) * 1024 + lane * 16];

    // prefetch registers: tile k in flight while tile k-1 computes
    f32x4 A00, A01, A10, A11, B00, B01, B10, B11;
    A00 = *(const f32x4*)(xa);     A01 = *(const f32x4*)(xa + 4);
    A10 = *(const f32x4*)(xb);     A11 = *(const f32x4*)(xb + 4);
    B00 = *(const f32x4*)(wa);     B01 = *(const f32x4*)(wa + 4);
    B10 = *(const f32x4*)(wb);     B11 = *(const f32x4*)(wb + 4);
    int koff = 0;

    auto stage = [&](int buf) {
        unsigned char* w = wr + buf * 16384;
        *(bf16x8*)(w +     0) = cvt8(A00, A01);   // A rows 0..63
        *(bf16x8*)(w +  4096) = cvt8(A10, A11);   // A rows 64..127
        *(bf16x8*)(w +  8192) = cvt8(B00, B01);   // B rows 0..63
        *(bf16x8*)(w + 12288) = cvt8(B10, B11);   // B rows 64..127
        // issue next tile's loads; wrap on last iter (harmless re-read of k=0)
        koff = (koff + BK) & (IN_F - 1);
        A00 = *(const f32x4*)(xa + koff); A01 = *(const f32x4*)(xa + koff + 4);
        A10 = *(const f32x4*)(xb + koff); A11 = *(const f32x4*)(xb + koff + 4);
        B00 = *(const f32x4*)(wa + koff); B01 = *(const f32x4*)(wa + koff + 4);
        B10 = *(const f32x4*)(wb + koff); B11 = *(const f32x4*)(wb + koff + 4);
    };

    auto compute = [&](int buf) {
        const unsigned char* ra = rdA + buf * 16384;
        const unsigned char* rb = rdB + buf * 16384;
        bf16x8 af[4], bfr[4];
        #pragma unroll
        for (int t = 0; t < 4; ++t) af[t]  = *(const bf16x8*)(ra + t * 1024);
        #pragma unroll
        for (int t = 0; t < 4; ++t) bfr[t] = *(const bf16x8*)(rb + t * 1024);
        #pragma unroll
        for (int i = 0; i < 4; ++i)
            #pragma unroll
            for (int j = 0; j < 4; ++j)
                acc[i][j] = __builtin_amdgcn_mfma_f32_16x16x32_bf16(af[i], bfr[j], acc[i][j], 0, 0, 0);
    };

    #pragma unroll 1
    for (int it = 0; it < IN_F / BK; it += 2) {
        stage(0);
        LDS_SYNC();
        compute(0);
        stage(1);
        LDS_SYNC();
        compute(1);
    }

    // Epilogue: bias + cyclic activation; selector = col%4 = lane&3 (branchless)
    const int s = lane & 3;
    const float kmul = (s == 0) ? -2.f : -1.f;
    const float aa   = (s == 0) ?  2.f :  1.f;
    const float cc   = (s == 0) ? -1.f :  0.f;
    const bool  is_sin  = (s == 1);
    const bool  is_relu = (s == 2);

    #pragma unroll
    for (int j = 0; j < 4; ++j) {
        const int gc = n0 + wn + j * 16 + lrow;
        const float bv = bias[gc];
        #pragma unroll
        for (int i = 0; i < 4; ++i) {
            const int gr0 = m0 + wm + i * 16 + quad * 4;
            float* op = O + (size_t)gr0 * OUT_F + gc;
            #pragma unroll
            for (int r = 0; r < 4; ++r) {
                const float y = acc[i][j][r] + bv;
                const float e = __expf(kmul * y);
                const float g = fmaf(aa, __builtin_amdgcn_rcpf(1.f + e), cc);
                const float sv = __sinf(y);
                const float rv = fmaxf(y, 0.f);
                const float res = is_sin ? sv : (is_relu ? rv : g);
                op[(size_t)r * OUT_F] = res;
            }
        }
    }
}

extern "C" void kernel_launch(void* const* d_in, const int* in_sizes, int n_in,
                              void* d_out, int out_size, void* d_ws, size_t ws_size,
                              hipStream_t stream) {
    const float* X = (const float*)d_in[0];
    const float* W = (const float*)d_in[1];
    const float* b = (const float*)d_in[2];
    float* O = (float*)d_out;

    const int grid = (B_ROWS / BM) * (OUT_F / BN);  // 4096 blocks
    fused_linear_act<<<grid, BDIM, 0, stream>>>(X, W, b, O);
}